// Round 8
// baseline (150.924 us; speedup 1.0000x reference)
//
#include <hip/hip_runtime.h>

typedef short bf16x8 __attribute__((ext_vector_type(8)));
typedef float f32x4 __attribute__((ext_vector_type(4)));

#define MFMA16(a, b, c) __builtin_amdgcn_mfma_f32_16x16x32_bf16(a, b, c, 0, 0, 0)

__device__ inline short f2bf(float f) {  // RNE
  unsigned u = __builtin_bit_cast(unsigned, f);
  u += 0x7FFFu + ((u >> 16) & 1u);
  return (short)(u >> 16);
}
// pack two fp32 -> 2 bf16 in one dword; round-half-up then v_perm byte-pack.
__device__ inline unsigned pack2(float lo, float hi) {
  unsigned a = __builtin_bit_cast(unsigned, lo) + 0x8000u;
  unsigned b = __builtin_bit_cast(unsigned, hi) + 0x8000u;
  return __builtin_amdgcn_perm(b, a, 0x07060302u);
}
// Async 16B global->LDS; lds ptr = wave-uniform lane-0 base, HW writes base+16*lane.
__device__ inline void async_cp16(const void* g, void* l) {
  __builtin_amdgcn_global_load_lds(
      (const __attribute__((address_space(1))) unsigned int*)g,
      (__attribute__((address_space(3))) unsigned int*)l, 16, 0, 0);
}
// XOR-swizzled tile, 32 chunks (8 shorts each) per row: slot column for global chunk c
// at row r swaps the low 3 bits by r. Staging stays lane-linear (conflict-free);
// fragment ds_read_b128 spreads 8 lanes per 4-bank group (wave64 minimum).
__device__ inline int swz5(int r, int c) {
  return ((r << 5) + ((c & ~7) | ((c ^ r) & 7))) << 3;
}

// ---------------------------------------------------------------------------
// ws layout (bytes) — poison outside written regions is finite bf16 (0xAAAA ~ -1e-13):
//   xmaj_bf  0        : 256x2048 bf16   rows>=210 poison (feeds discarded acc rows)
//   xmin_bf  1048576  : 256x2048 bf16
//   qs       2097152  : 256x1024 bf16   Qs (pre-scaled 1/32); rows>=210 poison
//   kwb      2621440  : 320x1024 bf16   0..209=K, 210..274=wk, 275..287=0, 288+ poison
//   vt       3276800  : 1024x256 bf16   V^T [n][m], cols>=210 poison (x A-zero cols)
//   av       3932160  : 256x1024 bf16   A@V, rows>=210 poison (feeds discarded rows)
//   Sp       4456448  : 224x320  f32    S' = Qs @ [K;wk]^T (cols>=288 garbage, unread)
//   wqt      4743168  : 1024x2048 bf16  Wq^T
//   wkt      8937472  : 1024x2048 bf16  Wk^T
//   wvt      13131776 : 1024x2048 bf16  Wv^T
//   wot      17326080 : 1024x1024 bf16  Wo^T
// ---------------------------------------------------------------------------

// Prep: blocks [0,512) convert X_major/X_minor/wk to bf16, zero kwb pad rows;
// blocks [512,2048) transpose+convert Wq/Wk/Wv (64x64 tiles); [2048,2304) Wo.
__global__ __launch_bounds__(256) void k_prep(const float* __restrict__ xmaj,
                                              const float* __restrict__ xmin,
                                              const float* __restrict__ wkin,
                                              const float* __restrict__ Wq,
                                              const float* __restrict__ Wk,
                                              const float* __restrict__ Wv,
                                              const float* __restrict__ Wo,
                                              short* __restrict__ xmaj_bf,
                                              short* __restrict__ xmin_bf,
                                              short* __restrict__ kwb,
                                              short* __restrict__ wqt,
                                              short* __restrict__ wkt,
                                              short* __restrict__ wvt,
                                              short* __restrict__ wot) {
  __shared__ short tile[64][72];  // stride 72 shorts: 16B-aligned rows
  int b = blockIdx.x, t = threadIdx.x;
  if (b < 512) {
    int idx = b * 256 + t;
    if (idx < 107520) {  // 210*2048/4
      float4 v = ((const float4*)xmaj)[idx];
      ((uint2*)xmaj_bf)[idx] = make_uint2(pack2(v.x, v.y), pack2(v.z, v.w));
      float4 u = ((const float4*)xmin)[idx];
      ((uint2*)xmin_bf)[idx] = make_uint2(pack2(u.x, u.y), pack2(u.z, u.w));
    }
    if (idx < 16640) {  // 65*1024/4
      float4 v = ((const float4*)wkin)[idx];
      ((uint2*)(kwb + 210 * 1024))[idx] = make_uint2(pack2(v.x, v.y), pack2(v.z, v.w));
    }
    if (idx < 1664) ((uint4*)(kwb + 275 * 1024))[idx] = make_uint4(0, 0, 0, 0);
    return;
  }
  const float* W;
  short* Wt;
  int kt, nt, dstK;
  if (b < 2048) {
    int wi = (b - 512) >> 9, tl = (b - 512) & 511;
    W = wi == 0 ? Wq : (wi == 1 ? Wk : Wv);
    Wt = wi == 0 ? wqt : (wi == 1 ? wkt : wvt);
    kt = tl >> 4; nt = tl & 15; dstK = 2048;
  } else {
    int tl = b - 2048;
    W = Wo; Wt = wot; kt = tl >> 4; nt = tl & 15; dstK = 1024;
  }
  int k0 = kt * 64, n0 = nt * 64;
  int kp = t >> 4, nl4 = (t & 15) * 4;
  for (int h = 0; h < 2; ++h) {
    int kpp = kp + h * 16;
    const float* g = W + (size_t)(k0 + 2 * kpp) * 1024 + n0 + nl4;
    float4 u = *(const float4*)g;
    float4 v = *(const float4*)(g + 1024);
    *(unsigned*)&tile[nl4 + 0][2 * kpp] = pack2(u.x, v.x);
    *(unsigned*)&tile[nl4 + 1][2 * kpp] = pack2(u.y, v.y);
    *(unsigned*)&tile[nl4 + 2][2 * kpp] = pack2(u.z, v.z);
    *(unsigned*)&tile[nl4 + 3][2 * kpp] = pack2(u.w, v.w);
  }
  __syncthreads();
  int nl = t >> 2, cq = t & 3;
  for (int h = 0; h < 2; ++h) {
    int c = cq + h * 4;
    *(uint4*)(Wt + (size_t)(n0 + nl) * dstK + k0 + c * 8) = *(const uint4*)&tile[nl][c * 8];
  }
}

// QKV: [Xmaj@Wq*scale | Xmin@Wk | Xmin@Wv], all-bf16 async staging, BK=256, 8 phases.
// 192 blocks, XCD swizzle: 4 m-tiles sharing a weight tile land on one XCD.
__global__ __launch_bounds__(256, 1) void k_qkv(const short* __restrict__ xmaj,
                                                const short* __restrict__ xmin,
                                                const short* __restrict__ wqt,
                                                const short* __restrict__ wkt,
                                                const short* __restrict__ wvt,
                                                short* __restrict__ qs,
                                                short* __restrict__ kwb,
                                                short* __restrict__ vt) {
  __shared__ short As[64 * 256];  // 32 KB
  __shared__ short Bs[64 * 256];  // 32 KB
  int b = blockIdx.x, t = threadIdx.x;
  int x = b & 7, s = b >> 3;
  int ntile = x * 6 + (s >> 2), mtile = s & 3;
  int nn0 = ntile * 64;
  int mat = nn0 >> 10, ncol0 = nn0 & 1023, m0 = mtile * 64;
  const short* A = (mat == 0) ? xmaj : xmin;
  const short* Bt = (mat == 0) ? wqt : (mat == 1 ? wkt : wvt);
  int lane = t & 63, w = t >> 6;
  int wm = w >> 1, wn = w & 1;
  int l15 = lane & 15, l4 = lane >> 4;
  f32x4 acc[2][2] = {};

  for (int k0 = 0; k0 < 2048; k0 += 256) {
    __syncthreads();
#pragma unroll
    for (int j = 0; j < 8; ++j) {
      int sj = t + j * 256;
      int r = sj >> 5, c = sj & 31;
      int cg = (c & ~7) | ((c ^ r) & 7);
      async_cp16(A + (size_t)(m0 + r) * 2048 + k0 + cg * 8, &As[(j * 256 + w * 64) * 8]);
    }
#pragma unroll
    for (int j = 0; j < 8; ++j) {
      int sj = t + j * 256;
      int r = sj >> 5, c = sj & 31;
      int cg = (c & ~7) | ((c ^ r) & 7);
      async_cp16(Bt + (size_t)(ncol0 + r) * 2048 + k0 + cg * 8, &Bs[(j * 256 + w * 64) * 8]);
    }
    __syncthreads();
#pragma unroll
    for (int kk = 0; kk < 8; ++kk) {
      int c = kk * 4 + l4;
      int ra0 = wm * 32 + l15, ra1 = ra0 + 16;
      int rb0 = wn * 32 + l15, rb1 = rb0 + 16;
      bf16x8 a0 = *(const bf16x8*)&As[swz5(ra0, c)];
      bf16x8 a1 = *(const bf16x8*)&As[swz5(ra1, c)];
      bf16x8 b0 = *(const bf16x8*)&Bs[swz5(rb0, c)];
      bf16x8 b1 = *(const bf16x8*)&Bs[swz5(rb1, c)];
      acc[0][0] = MFMA16(a0, b0, acc[0][0]);
      acc[0][1] = MFMA16(a0, b1, acc[0][1]);
      acc[1][0] = MFMA16(a1, b0, acc[1][0]);
      acc[1][1] = MFMA16(a1, b1, acc[1][1]);
    }
  }

  if (mat < 2) {
    float scale = (mat == 0) ? 0.03125f : 1.0f;
    short* dst = (mat == 0) ? qs : kwb;
#pragma unroll
    for (int mi = 0; mi < 2; ++mi)
#pragma unroll
      for (int ni = 0; ni < 2; ++ni) {
        int r0 = m0 + wm * 32 + mi * 16 + l4 * 4;
        int c = ncol0 + wn * 32 + ni * 16 + l15;
        for (int j = 0; j < 4; ++j) {
          int r = r0 + j;
          if (r < 210) dst[r * 1024 + c] = f2bf(acc[mi][ni][j] * scale);
        }
      }
  } else {
    // V: transpose via LDS (reuse As, stride 72 for aligned uint4 reads), store vt[n][m]
    __syncthreads();
#pragma unroll
    for (int mi = 0; mi < 2; ++mi)
#pragma unroll
      for (int ni = 0; ni < 2; ++ni) {
        int nl = wn * 32 + ni * 16 + l15;
        int ml0 = wm * 32 + mi * 16 + l4 * 4;
        for (int j = 0; j < 4; ++j) As[nl * 72 + ml0 + j] = f2bf(acc[mi][ni][j]);
      }
    __syncthreads();
    for (int h = 0; h < 2; ++h) {
      int idx = t + h * 256;
      int nl = idx >> 3, c8 = idx & 7;
      int mg0 = m0 + c8 * 8;
      short* dstp = vt + (ncol0 + nl) * 256 + mg0;
      if (mg0 + 8 <= 210) {
        *(uint4*)dstp = *(const uint4*)&As[nl * 72 + c8 * 8];
      } else {
        for (int e = 0; e < 8; ++e)
          if (mg0 + e < 210) dstp[e] = As[nl * 72 + c8 * 8 + e];
      }
    }
  }
}

// S' = Qs @ [K;wk]^T -> Sp[224][320] fp32. 32x64 tiles, grid (5,7), BK=256, 4 phases.
__global__ __launch_bounds__(256, 1) void k_sprime(const short* __restrict__ qs,
                                                   const short* __restrict__ kwb,
                                                   float* __restrict__ Sp) {
  __shared__ short As2[32 * 256];  // 16 KB
  __shared__ short Bs2[64 * 256];  // 32 KB
  int n0 = blockIdx.x * 64, m0 = blockIdx.y * 32;
  int t = threadIdx.x, lane = t & 63, w = t >> 6;
  int l15 = lane & 15, l4 = lane >> 4;
  f32x4 acc[2] = {};

  for (int k0 = 0; k0 < 1024; k0 += 256) {
    __syncthreads();
#pragma unroll
    for (int j = 0; j < 4; ++j) {
      int sj = t + j * 256;
      int r = sj >> 5, c = sj & 31;
      int cg = (c & ~7) | ((c ^ r) & 7);
      async_cp16(qs + (size_t)(m0 + r) * 1024 + k0 + cg * 8, &As2[(j * 256 + w * 64) * 8]);
    }
#pragma unroll
    for (int j = 0; j < 8; ++j) {
      int sj = t + j * 256;
      int r = sj >> 5, c = sj & 31;
      int cg = (c & ~7) | ((c ^ r) & 7);
      async_cp16(kwb + (size_t)(n0 + r) * 1024 + k0 + cg * 8, &Bs2[(j * 256 + w * 64) * 8]);
    }
    __syncthreads();
#pragma unroll
    for (int kk = 0; kk < 8; ++kk) {
      int c = kk * 4 + l4;
      bf16x8 a0 = *(const bf16x8*)&As2[swz5(l15, c)];
      bf16x8 a1 = *(const bf16x8*)&As2[swz5(16 + l15, c)];
      bf16x8 bb = *(const bf16x8*)&Bs2[swz5(w * 16 + l15, c)];
      acc[0] = MFMA16(a0, bb, acc[0]);
      acc[1] = MFMA16(a1, bb, acc[1]);
    }
  }
#pragma unroll
  for (int mi = 0; mi < 2; ++mi) {
    int r0 = m0 + mi * 16 + l4 * 4;
    int col = n0 + w * 16 + l15;
    for (int j = 0; j < 4; ++j) Sp[(r0 + j) * 320 + col] = acc[mi][j];
  }
}

// Fused softmax + AV. grid(16,4): block (n,m) computes softmax for its 64-row strip
// from Sp (redundant across the 16 n-blocks; ~2 us of L2/L3 reads) directly into its
// LDS A-tile (no Abf buffer), overlapped with async V-tile staging, then one-shot
// K=256 MFMA. blockIdx.x==0 blocks also write fp32 A to d_out.
__global__ __launch_bounds__(256, 1) void k_av_smax(const float* __restrict__ Sp,
                                                    const int* __restrict__ table,
                                                    const short* __restrict__ vt,
                                                    short* __restrict__ av,
                                                    float* __restrict__ outA) {
  __shared__ short As[64 * 256];   // 32 KB  A-tile (bf16, swizzled)
  __shared__ short Bs[64 * 256];   // 32 KB  V^T tile
  __shared__ float Ls[64 * 212];   // 53 KB  per-row logit/exp scratch
  int n0 = blockIdx.x * 64, m0 = blockIdx.y * 64;
  int t = threadIdx.x, lane = t & 63, w = t >> 6;
  int wm = w >> 1, wn = w & 1;
  int l15 = lane & 15, l4 = lane >> 4;

  // issue B staging first so it overlaps the softmax
#pragma unroll
  for (int j = 0; j < 8; ++j) {
    int sj = t + j * 256;
    int r = sj >> 5, c = sj & 31;
    int cg = (c & ~7) | ((c ^ r) & 7);
    async_cp16(vt + (size_t)(n0 + r) * 256 + cg * 8, &Bs[(j * 256 + w * 64) * 8]);
  }

  // softmax: 4 threads per row (same wave, shfl width 4)
  int r = t >> 2, q = t & 3;
  int row = m0 + r;
  float* Lr = Ls + r * 212;
  if (row < 210) {
    const float* sp = Sp + (size_t)row * 320;
    const int* tr = table + (size_t)row * 210;
    float mx = -1e30f;
    for (int j = q; j < 210; j += 4) {
      int tb = tr[j];
      float lg = sp[j] + sp[210 + tb];
      Lr[j] = lg;
      mx = fmaxf(mx, lg);
    }
    for (int o = 2; o; o >>= 1) mx = fmaxf(mx, __shfl_xor(mx, o, 4));
    float sum = 0.0f;
    for (int j = q; j < 210; j += 4) {
      float e = __expf(Lr[j] - mx);
      Lr[j] = e;
      sum += e;
    }
    for (int o = 2; o; o >>= 1) sum += __shfl_xor(sum, o, 4);
    float inv = 1.0f / sum;
    bool wA = (n0 == 0);
    for (int j = q; j < 256; j += 4) {
      if (j < 210) {
        float a = Lr[j] * inv;
        As[swz5(r, j >> 3) + (j & 7)] = f2bf(a);
        if (wA) outA[(size_t)row * 210 + j] = a;
      } else {
        As[swz5(r, j >> 3) + (j & 7)] = 0;
      }
    }
  } else {
    for (int j = q; j < 256; j += 4) As[swz5(r, j >> 3) + (j & 7)] = 0;
  }
  __syncthreads();  // drains async B staging + LDS A writes

  f32x4 acc[2][2] = {};
#pragma unroll
  for (int kk = 0; kk < 8; ++kk) {
    int c = kk * 4 + l4;
    int ra0 = wm * 32 + l15, ra1 = ra0 + 16;
    int rb0 = wn * 32 + l15, rb1 = rb0 + 16;
    bf16x8 a0 = *(const bf16x8*)&As[swz5(ra0, c)];
    bf16x8 a1 = *(const bf16x8*)&As[swz5(ra1, c)];
    bf16x8 b0 = *(const bf16x8*)&Bs[swz5(rb0, c)];
    bf16x8 b1 = *(const bf16x8*)&Bs[swz5(rb1, c)];
    acc[0][0] = MFMA16(a0, b0, acc[0][0]);
    acc[0][1] = MFMA16(a0, b1, acc[0][1]);
    acc[1][0] = MFMA16(a1, b0, acc[1][0]);
    acc[1][1] = MFMA16(a1, b1, acc[1][1]);
  }
#pragma unroll
  for (int mi = 0; mi < 2; ++mi)
#pragma unroll
    for (int ni = 0; ni < 2; ++ni) {
      int r0 = m0 + wm * 32 + mi * 16 + l4 * 4;
      int c = n0 + wn * 32 + ni * 16 + l15;
      for (int j = 0; j < 4; ++j) {
        int rr = r0 + j;
        if (rr < 210) av[rr * 1024 + c] = f2bf(acc[mi][ni][j]);
      }
    }
}

// Y = AV @ Wo via wot[n][k]. 64x64 tiles, grid(16,4), BK=256, 4 phases. fp32 out.
__global__ __launch_bounds__(256, 1) void k_y(const short* __restrict__ av,
                                              const short* __restrict__ wot,
                                              float* __restrict__ outY) {
  __shared__ short As[64 * 256];
  __shared__ short Bs[64 * 256];
  int n0 = blockIdx.x * 64, m0 = blockIdx.y * 64;
  int t = threadIdx.x, lane = t & 63, w = t >> 6;
  int wm = w >> 1, wn = w & 1;
  int l15 = lane & 15, l4 = lane >> 4;
  f32x4 acc[2][2] = {};

  for (int k0 = 0; k0 < 1024; k0 += 256) {
    __syncthreads();
#pragma unroll
    for (int j = 0; j < 8; ++j) {
      int sj = t + j * 256;
      int r = sj >> 5, c = sj & 31;
      int cg = (c & ~7) | ((c ^ r) & 7);
      async_cp16(av + (size_t)(m0 + r) * 1024 + k0 + cg * 8, &As[(j * 256 + w * 64) * 8]);
      async_cp16(wot + (size_t)(n0 + r) * 1024 + k0 + cg * 8, &Bs[(j * 256 + w * 64) * 8]);
    }
    __syncthreads();
#pragma unroll
    for (int kk = 0; kk < 8; ++kk) {
      int c = kk * 4 + l4;
      int ra0 = wm * 32 + l15, ra1 = ra0 + 16;
      int rb0 = wn * 32 + l15, rb1 = rb0 + 16;
      bf16x8 a0 = *(const bf16x8*)&As[swz5(ra0, c)];
      bf16x8 a1 = *(const bf16x8*)&As[swz5(ra1, c)];
      bf16x8 b0 = *(const bf16x8*)&Bs[swz5(rb0, c)];
      bf16x8 b1 = *(const bf16x8*)&Bs[swz5(rb1, c)];
      acc[0][0] = MFMA16(a0, b0, acc[0][0]);
      acc[0][1] = MFMA16(a0, b1, acc[0][1]);
      acc[1][0] = MFMA16(a1, b0, acc[1][0]);
      acc[1][1] = MFMA16(a1, b1, acc[1][1]);
    }
  }
#pragma unroll
  for (int mi = 0; mi < 2; ++mi)
#pragma unroll
    for (int ni = 0; ni < 2; ++ni) {
      int r0 = m0 + wm * 32 + mi * 16 + l4 * 4;
      int c = n0 + wn * 32 + ni * 16 + l15;
      for (int j = 0; j < 4; ++j) {
        int r = r0 + j;
        if (r < 210) outY[r * 1024 + c] = acc[mi][ni][j];
      }
    }
}

extern "C" void kernel_launch(void* const* d_in, const int* in_sizes, int n_in,
                              void* d_out, int out_size, void* d_ws, size_t ws_size,
                              hipStream_t stream) {
  const float* Xmaj = (const float*)d_in[0];
  const float* Xmin = (const float*)d_in[1];
  const float* Wq = (const float*)d_in[2];
  const float* Wk = (const float*)d_in[3];
  const float* Wv = (const float*)d_in[4];
  const float* Wo = (const float*)d_in[5];
  const float* wk = (const float*)d_in[6];
  const int* table = (const int*)d_in[7];

  char* ws = (char*)d_ws;
  short* xmaj_bf = (short*)(ws + 0);
  short* xmin_bf = (short*)(ws + 1048576);
  short* qs = (short*)(ws + 2097152);
  short* kwb = (short*)(ws + 2621440);
  short* vt = (short*)(ws + 3276800);
  short* av = (short*)(ws + 3932160);
  float* Sp = (float*)(ws + 4456448);
  short* wqt = (short*)(ws + 4743168);
  short* wkt = (short*)(ws + 8937472);
  short* wvt = (short*)(ws + 13131776);
  short* wot = (short*)(ws + 17326080);

  float* outY = (float*)d_out;           // 210*1024 fp32
  float* outA = (float*)d_out + 215040;  // 210*210 fp32

  k_prep<<<2304, 256, 0, stream>>>(Xmaj, Xmin, wk, Wq, Wk, Wv, Wo,
                                   xmaj_bf, xmin_bf, kwb, wqt, wkt, wvt, wot);
  k_qkv<<<192, 256, 0, stream>>>(xmaj_bf, xmin_bf, wqt, wkt, wvt, qs, kwb, vt);
  k_sprime<<<dim3(5, 7), 256, 0, stream>>>(qs, kwb, Sp);
  k_av_smax<<<dim3(16, 4), 256, 0, stream>>>(Sp, table, vt, av, outA);
  k_y<<<dim3(16, 4), 256, 0, stream>>>(av, wot, outY);
}

// Round 9
// 136.302 us; speedup vs baseline: 1.1073x; 1.1073x over previous
//
#include <hip/hip_runtime.h>

typedef short bf16x8 __attribute__((ext_vector_type(8)));
typedef float f32x4 __attribute__((ext_vector_type(4)));

#define MFMA16(a, b, c) __builtin_amdgcn_mfma_f32_16x16x32_bf16(a, b, c, 0, 0, 0)

__device__ inline short f2bf(float f) {  // RNE
  unsigned u = __builtin_bit_cast(unsigned, f);
  u += 0x7FFFu + ((u >> 16) & 1u);
  return (short)(u >> 16);
}
// two fp32 -> 2 bf16 in one dword; round-half-up then v_perm byte-pack.
__device__ inline unsigned pack2(float lo, float hi) {
  unsigned a = __builtin_bit_cast(unsigned, lo) + 0x8000u;
  unsigned b = __builtin_bit_cast(unsigned, hi) + 0x8000u;
  return __builtin_amdgcn_perm(b, a, 0x07060302u);
}
// Async 16B global->LDS; lds ptr = wave-uniform lane-0 base, HW writes base+16*lane.
__device__ inline void async_cp16(const void* g, void* l) {
  __builtin_amdgcn_global_load_lds(
      (const __attribute__((address_space(1))) unsigned int*)g,
      (__attribute__((address_space(3))) unsigned int*)l, 16, 0, 0);
}
// bf16 tile, 16 chunks (8 shorts) per row, low-3-bit XOR swizzle (returns short index).
#define SWZ(r, c) ((((r) << 4) + ((c) ^ ((r) & 7))) << 3)
// 32-chunk variant (k_av, K=256 rows).
__device__ inline int swz5(int r, int c) {
  return ((r << 5) + ((c & ~7) | ((c ^ r) & 7))) << 3;
}
// fp32 staging chunk swizzle (self-inverse): slot c holds global chunk xsw(r,c).
__device__ inline int xsw(int r, int c) { return (c & ~7) | ((c ^ r) & 7); }

// ---------------------------------------------------------------------------
// ws layout (bytes) — poison outside written regions is finite bf16, audited safe:
//   qs   0       : 256x1024 bf16  Qs (pre-scaled 1/32); rows>=210 poison (discarded)
//   kwb  524288  : 320x1024 bf16  0..209=K, 210..274=wk, 275..287=0, 288+ poison
//   vt   1179648 : 1024x256 bf16  V^T [n][m]; cols>=210 poison (x zero A cols)
//   Abf  1703936 : 256x256  bf16  A padded, zeros outside 210x210 (k_softmax writes all)
//   av   1835008 : 256x1024 bf16  A@V; rows>=210 poison (discarded)
//   Sp   2359296 : 224x320  f32   S'; cols>=288 / rows>=210 garbage (unread)
//   wot  2646016 : 1024x1024 bf16 Wo^T (k_qkv tail blocks)
// ---------------------------------------------------------------------------

// QKV GEMM with fully fused prep. Blocks 0..191: 64x64 tiles (XCD swizzle: the 4
// m-tiles sharing a weight strip land on one XCD), BK=128, 16 phases. fp32 X and W
// staged async into double-buffered Xs/Ws; W transpose-packed to bf16 Bs in-LDS;
// A-fragments packed inline from Xs. Pipeline: issue p+1 right after the top
// __syncthreads (whose vmcnt(0) is p's intended drain); raw lgkmcnt-only barrier
// between repack and MFMA keeps p+1's loads in flight (no mid-phase vmcnt(0)).
// Blocks 192..193: wk convert + kwb zero. Blocks 194..449: Wo transpose tiles.
__global__ __launch_bounds__(256, 1) void k_qkv(const float* __restrict__ xmaj,
                                                const float* __restrict__ xmin,
                                                const float* __restrict__ Wq,
                                                const float* __restrict__ Wk,
                                                const float* __restrict__ Wv,
                                                const float* __restrict__ Wo,
                                                const float* __restrict__ wkin,
                                                short* __restrict__ qs,
                                                short* __restrict__ kwb,
                                                short* __restrict__ vt,
                                                short* __restrict__ wot) {
  __shared__ float Xs[2][64 * 128];   // 64 KB  fp32 A staging [m][128k], xsw chunks
  __shared__ float Ws[2][128 * 64];   // 64 KB  fp32 W staging [k][64n], xsw chunks
  __shared__ short Bs[64 * 128];      // 16 KB  bf16 B tile [n][128k], SWZ chunks
  int b = blockIdx.x, t = threadIdx.x;

  if (b >= 192) {
    if (b < 194) {  // wk convert (65x1024) + zero kwb rows 275..287
      int idx = (b - 192) * 256 + t;
      const float4* src = (const float4*)wkin;
      uint2* dst = (uint2*)(kwb + 210 * 1024);
      for (int i = idx; i < 16640; i += 512) {
        float4 v = src[i];
        dst[i] = make_uint2(pack2(v.x, v.y), pack2(v.z, v.w));
      }
      for (int i = idx; i < 1664; i += 512)
        ((uint4*)(kwb + 275 * 1024))[i] = make_uint4(0, 0, 0, 0);
    } else {  // Wo transpose: 256 tiles of 64x64, via LDS (alias Bs region)
      short(*tile)[72] = (short(*)[72])Bs;
      int tl = b - 194;
      int k0 = (tl >> 4) * 64, n0 = (tl & 15) * 64;
      int kp = t >> 4, nl4 = (t & 15) * 4;
#pragma unroll
      for (int h = 0; h < 2; ++h) {
        int kpp = kp + h * 16;
        const float* g = Wo + (size_t)(k0 + 2 * kpp) * 1024 + n0 + nl4;
        float4 u = *(const float4*)g;
        float4 v = *(const float4*)(g + 1024);
        *(unsigned*)&tile[nl4 + 0][2 * kpp] = pack2(u.x, v.x);
        *(unsigned*)&tile[nl4 + 1][2 * kpp] = pack2(u.y, v.y);
        *(unsigned*)&tile[nl4 + 2][2 * kpp] = pack2(u.z, v.z);
        *(unsigned*)&tile[nl4 + 3][2 * kpp] = pack2(u.w, v.w);
      }
      __syncthreads();
      int nl = t >> 2, cq = t & 3;
#pragma unroll
      for (int h = 0; h < 2; ++h) {
        int c = cq + h * 4;
        *(uint4*)(wot + (size_t)(n0 + nl) * 1024 + k0 + c * 8) = *(const uint4*)&tile[nl][c * 8];
      }
    }
    return;
  }

  int x = b & 7, s = b >> 3;
  int ntile = x * 6 + (s >> 2), mtile = s & 3;
  int nn0 = ntile * 64;
  int mat = nn0 >> 10, ncol0 = nn0 & 1023, m0 = mtile * 64;
  const float* Xa = (mat == 0) ? xmaj : xmin;
  const float* Wp = (mat == 0) ? Wq : (mat == 1 ? Wk : Wv);
  int lane = t & 63, w = t >> 6;
  int wm = w >> 1, wn = w & 1;
  int l15 = lane & 15, l4 = lane >> 4;
  f32x4 acc[2][2] = {};

  auto issue = [&](int p) {
    int k0 = p * 128;
    float* X = &Xs[p & 1][0];
    float* W2 = &Ws[p & 1][0];
#pragma unroll
    for (int j = 0; j < 8; ++j) {  // Xs: 64 rows x 32 fp32-chunks
      int sj = t + j * 256;
      int r = sj >> 5, c = sj & 31;
      int row = m0 + r;
      row = row > 209 ? 209 : row;  // clamp: no OOB reads of X fp32
      async_cp16(Xa + (size_t)row * 2048 + k0 + xsw(r, c) * 4, &X[(j * 256 + w * 64) * 4]);
    }
#pragma unroll
    for (int j = 0; j < 8; ++j) {  // Ws: 128 rows x 16 fp32-chunks
      int sj = t + j * 256;
      int r = sj >> 4, c = sj & 15;
      async_cp16(Wp + (size_t)(k0 + r) * 1024 + ncol0 + xsw(r, c) * 4, &W2[(j * 256 + w * 64) * 4]);
    }
  };

  issue(0);
#pragma unroll 1
  for (int p = 0; p < 16; ++p) {
    __syncthreads();          // compiler emits vmcnt(0): drains phase p's async loads
    if (p < 15) issue(p + 1); // other buffer halves; fly through repack+MFMA below
    {  // repack: Ws[p&1] fp32 [k][n] -> Bs bf16 [n][k] (SWZ)
      const float* W2 = &Ws[p & 1][0];
#pragma unroll
      for (int h = 0; h < 4; ++h) {
        int kp = (t >> 4) + 16 * h, nq = t & 15;
        int r0 = 2 * kp, r1 = r0 + 1;
        float4 u = *(const float4*)&W2[r0 * 64 + xsw(r0, nq) * 4];
        float4 v = *(const float4*)&W2[r1 * 64 + xsw(r1, nq) * 4];
        int kc = kp >> 2, e = r0 & 7;
        *(unsigned*)&Bs[SWZ(nq * 4 + 0, kc) + e] = pack2(u.x, v.x);
        *(unsigned*)&Bs[SWZ(nq * 4 + 1, kc) + e] = pack2(u.y, v.y);
        *(unsigned*)&Bs[SWZ(nq * 4 + 2, kc) + e] = pack2(u.z, v.z);
        *(unsigned*)&Bs[SWZ(nq * 4 + 3, kc) + e] = pack2(u.w, v.w);
      }
    }
    // LDS-only barrier: make Bs visible WITHOUT draining p+1's in-flight vmem.
    asm volatile("s_waitcnt lgkmcnt(0)\ns_barrier" ::: "memory");
    {  // MFMA; A-fragments packed inline from Xs fp32
      const float* X = &Xs[p & 1][0];
#pragma unroll
      for (int kk = 0; kk < 4; ++kk) {
        int c = kk * 4 + l4;
        int ra0 = wm * 32 + l15, ra1 = ra0 + 16;
        int rb0 = wn * 32 + l15, rb1 = rb0 + 16;
        float4 u0 = *(const float4*)&X[ra0 * 128 + xsw(ra0, 2 * c) * 4];
        float4 v0 = *(const float4*)&X[ra0 * 128 + xsw(ra0, 2 * c + 1) * 4];
        float4 u1 = *(const float4*)&X[ra1 * 128 + xsw(ra1, 2 * c) * 4];
        float4 v1 = *(const float4*)&X[ra1 * 128 + xsw(ra1, 2 * c + 1) * 4];
        uint4 pa0 = make_uint4(pack2(u0.x, u0.y), pack2(u0.z, u0.w), pack2(v0.x, v0.y), pack2(v0.z, v0.w));
        uint4 pa1 = make_uint4(pack2(u1.x, u1.y), pack2(u1.z, u1.w), pack2(v1.x, v1.y), pack2(v1.z, v1.w));
        bf16x8 a0 = __builtin_bit_cast(bf16x8, pa0);
        bf16x8 a1 = __builtin_bit_cast(bf16x8, pa1);
        bf16x8 b0 = *(const bf16x8*)&Bs[SWZ(rb0, c)];
        bf16x8 b1 = *(const bf16x8*)&Bs[SWZ(rb1, c)];
        acc[0][0] = MFMA16(a0, b0, acc[0][0]);
        acc[0][1] = MFMA16(a0, b1, acc[0][1]);
        acc[1][0] = MFMA16(a1, b0, acc[1][0]);
        acc[1][1] = MFMA16(a1, b1, acc[1][1]);
      }
    }
  }

  if (mat < 2) {
    float scale = (mat == 0) ? 0.03125f : 1.0f;
    short* dst = (mat == 0) ? qs : kwb;
#pragma unroll
    for (int mi = 0; mi < 2; ++mi)
#pragma unroll
      for (int ni = 0; ni < 2; ++ni) {
        int r0 = m0 + wm * 32 + mi * 16 + l4 * 4;
        int c = ncol0 + wn * 32 + ni * 16 + l15;
        for (int j = 0; j < 4; ++j) {
          int r = r0 + j;
          if (r < 210) dst[r * 1024 + c] = f2bf(acc[mi][ni][j] * scale);
        }
      }
  } else {
    // V: transpose via LDS (Bs as scratch, stride 72), store vt[n][m]
    __syncthreads();
    short* scr = Bs;
#pragma unroll
    for (int mi = 0; mi < 2; ++mi)
#pragma unroll
      for (int ni = 0; ni < 2; ++ni) {
        int nl = wn * 32 + ni * 16 + l15;
        int ml0 = wm * 32 + mi * 16 + l4 * 4;
        for (int j = 0; j < 4; ++j) scr[nl * 72 + ml0 + j] = f2bf(acc[mi][ni][j]);
      }
    __syncthreads();
    for (int h = 0; h < 2; ++h) {
      int idx = t + h * 256;
      int nl = idx >> 3, c8 = idx & 7;
      int mg0 = m0 + c8 * 8;
      short* dstp = vt + (ncol0 + nl) * 256 + mg0;
      if (mg0 + 8 <= 210) {
        *(uint4*)dstp = *(const uint4*)&scr[nl * 72 + c8 * 8];
      } else {
        for (int e = 0; e < 8; ++e)
          if (mg0 + e < 210) dstp[e] = scr[nl * 72 + c8 * 8 + e];
      }
    }
  }
}

// S' = Qs @ [K;wk]^T -> Sp[224][320] fp32. 32x64 tiles, grid (5,7), BK=128, 8 phases,
// double-buffered: issue p+1 after the top barrier -> overlaps MFMA p legally.
__global__ __launch_bounds__(256, 1) void k_sprime(const short* __restrict__ qs,
                                                   const short* __restrict__ kwb,
                                                   float* __restrict__ Sp) {
  __shared__ short As[2][32 * 128];
  __shared__ short Bs[2][64 * 128];
  int n0 = blockIdx.x * 64, m0 = blockIdx.y * 32;
  int t = threadIdx.x, lane = t & 63, w = t >> 6;
  int l15 = lane & 15, l4 = lane >> 4;
  f32x4 acc[2] = {};

  auto issue = [&](int p) {
    int k0 = p * 128, d = p & 1;
#pragma unroll
    for (int j = 0; j < 2; ++j) {
      int sj = t + j * 256;
      int r = sj >> 4, cg = (sj & 15) ^ (r & 7);
      async_cp16(qs + (size_t)(m0 + r) * 1024 + k0 + cg * 8, &As[d][(j * 256 + w * 64) * 8]);
    }
#pragma unroll
    for (int j = 0; j < 4; ++j) {
      int sj = t + j * 256;
      int r = sj >> 4, cg = (sj & 15) ^ (r & 7);
      async_cp16(kwb + (size_t)(n0 + r) * 1024 + k0 + cg * 8, &Bs[d][(j * 256 + w * 64) * 8]);
    }
  };

  issue(0);
#pragma unroll 1
  for (int p = 0; p < 8; ++p) {
    __syncthreads();           // drains p (p+1 not yet issued)
    if (p < 7) issue(p + 1);   // flies during MFMA p, drained at next top barrier
    int d = p & 1;
#pragma unroll
    for (int kk = 0; kk < 4; ++kk) {
      int c = kk * 4 + l4;
      bf16x8 a0 = *(const bf16x8*)&As[d][SWZ(l15, c)];
      bf16x8 a1 = *(const bf16x8*)&As[d][SWZ(16 + l15, c)];
      bf16x8 bb = *(const bf16x8*)&Bs[d][SWZ(w * 16 + l15, c)];
      acc[0] = MFMA16(a0, bb, acc[0]);
      acc[1] = MFMA16(a1, bb, acc[1]);
    }
  }
#pragma unroll
  for (int mi = 0; mi < 2; ++mi) {
    int r0 = m0 + mi * 16 + l4 * 4;
    int col = n0 + w * 16 + l15;
    for (int j = 0; j < 4; ++j) Sp[(r0 + j) * 320 + col] = acc[mi][j];
  }
}

// softmax rows: logits[i][j] = Sp[i][j] + Sp[i][210+table[i][j]]; fp32 A to d_out,
// bf16 Abf (all 256x256 written: zeros outside 210x210).
__global__ __launch_bounds__(256) void k_softmax(const float* __restrict__ Sp,
                                                 const int* __restrict__ table,
                                                 short* __restrict__ Abf,
                                                 float* __restrict__ outA) {
  int i = blockIdx.x, t = threadIdx.x;
  if (i >= 210) {
    Abf[i * 256 + t] = 0;
    return;
  }
  __shared__ float srow[288];
  __shared__ float red[4];
  for (int j = t; j < 288; j += 256) srow[j] = Sp[i * 320 + j];
  __syncthreads();
  float logit = -1e30f;
  if (t < 210) {
    int tb = table[i * 210 + t];
    logit = srow[t] + srow[210 + tb];
  }
  float m = logit;
  for (int o = 32; o; o >>= 1) m = fmaxf(m, __shfl_xor(m, o));
  if ((t & 63) == 0) red[t >> 6] = m;
  __syncthreads();
  m = fmaxf(fmaxf(red[0], red[1]), fmaxf(red[2], red[3]));
  float e = (t < 210) ? __expf(logit - m) : 0.0f;
  float s = e;
  for (int o = 32; o; o >>= 1) s += __shfl_xor(s, o);
  __syncthreads();
  if ((t & 63) == 0) red[t >> 6] = s;
  __syncthreads();
  s = red[0] + red[1] + red[2] + red[3];
  float a = e / s;
  Abf[i * 256 + t] = (t < 210) ? f2bf(a) : (short)0;
  if (t < 210) outA[i * 210 + t] = a;
}

// AV = A(pad bf16) @ V via vt[n][k]. 64x64 tiles, grid(16,4), single K=256 pass.
__global__ __launch_bounds__(256, 1) void k_av(const short* __restrict__ Abf,
                                               const short* __restrict__ vt,
                                               short* __restrict__ av) {
  __shared__ short As[64 * 256];
  __shared__ short Bs[64 * 256];
  int n0 = blockIdx.x * 64, m0 = blockIdx.y * 64;
  int t = threadIdx.x, lane = t & 63, w = t >> 6;
  int wm = w >> 1, wn = w & 1;
  int l15 = lane & 15, l4 = lane >> 4;

#pragma unroll
  for (int j = 0; j < 8; ++j) {
    int sj = t + j * 256;
    int r = sj >> 5, c = sj & 31;
    int cg = (c & ~7) | ((c ^ r) & 7);
    async_cp16(Abf + (size_t)(m0 + r) * 256 + cg * 8, &As[(j * 256 + w * 64) * 8]);
    async_cp16(vt + (size_t)(n0 + r) * 256 + cg * 8, &Bs[(j * 256 + w * 64) * 8]);
  }
  __syncthreads();

  f32x4 acc[2][2] = {};
#pragma unroll
  for (int kk = 0; kk < 8; ++kk) {
    int c = kk * 4 + l4;
    int ra0 = wm * 32 + l15, ra1 = ra0 + 16;
    int rb0 = wn * 32 + l15, rb1 = rb0 + 16;
    bf16x8 a0 = *(const bf16x8*)&As[swz5(ra0, c)];
    bf16x8 a1 = *(const bf16x8*)&As[swz5(ra1, c)];
    bf16x8 b0 = *(const bf16x8*)&Bs[swz5(rb0, c)];
    bf16x8 b1 = *(const bf16x8*)&Bs[swz5(rb1, c)];
    acc[0][0] = MFMA16(a0, b0, acc[0][0]);
    acc[0][1] = MFMA16(a0, b1, acc[0][1]);
    acc[1][0] = MFMA16(a1, b0, acc[1][0]);
    acc[1][1] = MFMA16(a1, b1, acc[1][1]);
  }
#pragma unroll
  for (int mi = 0; mi < 2; ++mi)
#pragma unroll
    for (int ni = 0; ni < 2; ++ni) {
      int r0 = m0 + wm * 32 + mi * 16 + l4 * 4;
      int c = n0 + wn * 32 + ni * 16 + l15;
      for (int j = 0; j < 4; ++j) {
        int r = r0 + j;
        if (r < 210) av[r * 1024 + c] = f2bf(acc[mi][ni][j]);
      }
    }
}

// Y = AV @ Wo via wot[n][k]. 64x64 tiles, grid(16,4), BK=128, 8 phases, dbuf. fp32 out.
__global__ __launch_bounds__(256, 1) void k_y(const short* __restrict__ av,
                                              const short* __restrict__ wot,
                                              float* __restrict__ outY) {
  __shared__ short As[2][64 * 128];
  __shared__ short Bs[2][64 * 128];
  int n0 = blockIdx.x * 64, m0 = blockIdx.y * 64;
  int t = threadIdx.x, lane = t & 63, w = t >> 6;
  int wm = w >> 1, wn = w & 1;
  int l15 = lane & 15, l4 = lane >> 4;
  f32x4 acc[2][2] = {};

  auto issue = [&](int p) {
    int k0 = p * 128, d = p & 1;
#pragma unroll
    for (int j = 0; j < 4; ++j) {
      int sj = t + j * 256;
      int r = sj >> 4, cg = (sj & 15) ^ (r & 7);
      async_cp16(av + (size_t)(m0 + r) * 1024 + k0 + cg * 8, &As[d][(j * 256 + w * 64) * 8]);
      async_cp16(wot + (size_t)(n0 + r) * 1024 + k0 + cg * 8, &Bs[d][(j * 256 + w * 64) * 8]);
    }
  };

  issue(0);
#pragma unroll 1
  for (int p = 0; p < 8; ++p) {
    __syncthreads();
    if (p < 7) issue(p + 1);
    int d = p & 1;
#pragma unroll
    for (int kk = 0; kk < 4; ++kk) {
      int c = kk * 4 + l4;
      int ra0 = wm * 32 + l15, ra1 = ra0 + 16;
      int rb0 = wn * 32 + l15, rb1 = rb0 + 16;
      bf16x8 a0 = *(const bf16x8*)&As[d][SWZ(ra0, c)];
      bf16x8 a1 = *(const bf16x8*)&As[d][SWZ(ra1, c)];
      bf16x8 b0 = *(const bf16x8*)&Bs[d][SWZ(rb0, c)];
      bf16x8 b1 = *(const bf16x8*)&Bs[d][SWZ(rb1, c)];
      acc[0][0] = MFMA16(a0, b0, acc[0][0]);
      acc[0][1] = MFMA16(a0, b1, acc[0][1]);
      acc[1][0] = MFMA16(a1, b0, acc[1][0]);
      acc[1][1] = MFMA16(a1, b1, acc[1][1]);
    }
  }
#pragma unroll
  for (int mi = 0; mi < 2; ++mi)
#pragma unroll
    for (int ni = 0; ni < 2; ++ni) {
      int r0 = m0 + wm * 32 + mi * 16 + l4 * 4;
      int c = n0 + wn * 32 + ni * 16 + l15;
      for (int j = 0; j < 4; ++j) {
        int r = r0 + j;
        if (r < 210) outY[r * 1024 + c] = acc[mi][ni][j];
      }
    }
}

extern "C" void kernel_launch(void* const* d_in, const int* in_sizes, int n_in,
                              void* d_out, int out_size, void* d_ws, size_t ws_size,
                              hipStream_t stream) {
  const float* Xmaj = (const float*)d_in[0];
  const float* Xmin = (const float*)d_in[1];
  const float* Wq = (const float*)d_in[2];
  const float* Wk = (const float*)d_in[3];
  const float* Wv = (const float*)d_in[4];
  const float* Wo = (const float*)d_in[5];
  const float* wk = (const float*)d_in[6];
  const int* table = (const int*)d_in[7];

  char* ws = (char*)d_ws;
  short* qs = (short*)(ws + 0);
  short* kwb = (short*)(ws + 524288);
  short* vt = (short*)(ws + 1179648);
  short* Abf = (short*)(ws + 1703936);
  short* av = (short*)(ws + 1835008);
  float* Sp = (float*)(ws + 2359296);
  short* wot = (short*)(ws + 2646016);

  float* outY = (float*)d_out;           // 210*1024 fp32
  float* outA = (float*)d_out + 215040;  // 210*210 fp32

  k_qkv<<<450, 256, 0, stream>>>(Xmaj, Xmin, Wq, Wk, Wv, Wo, wk, qs, kwb, vt, wot);
  k_sprime<<<dim3(5, 7), 256, 0, stream>>>(qs, kwb, Sp);
  k_softmax<<<256, 256, 0, stream>>>(Sp, table, Abf, outA);
  k_av<<<dim3(16, 4), 256, 0, stream>>>(Abf, vt, av);
  k_y<<<dim3(16, 4), 256, 0, stream>>>(av, wot, outY);
}

// Round 10
// 120.832 us; speedup vs baseline: 1.2490x; 1.1280x over previous
//
#include <hip/hip_runtime.h>

typedef short bf16x8 __attribute__((ext_vector_type(8)));
typedef float f32x4 __attribute__((ext_vector_type(4)));

#define MFMA16(a, b, c) __builtin_amdgcn_mfma_f32_16x16x32_bf16(a, b, c, 0, 0, 0)

__device__ inline short f2bf(float f) {  // RNE
  unsigned u = __builtin_bit_cast(unsigned, f);
  u += 0x7FFFu + ((u >> 16) & 1u);
  return (short)(u >> 16);
}
// two fp32 -> 2 bf16 in one dword; round-half-up then v_perm byte-pack.
__device__ inline unsigned pack2(float lo, float hi) {
  unsigned a = __builtin_bit_cast(unsigned, lo) + 0x8000u;
  unsigned b = __builtin_bit_cast(unsigned, hi) + 0x8000u;
  return __builtin_amdgcn_perm(b, a, 0x07060302u);
}
// Async 16B global->LDS; lds ptr = wave-uniform lane-0 base, HW writes base+16*lane.
__device__ inline void async_cp16(const void* g, void* l) {
  __builtin_amdgcn_global_load_lds(
      (const __attribute__((address_space(1))) unsigned int*)g,
      (__attribute__((address_space(3))) unsigned int*)l, 16, 0, 0);
}
// bf16 tile, 16 chunks (8 shorts) per row, low-3-bit XOR swizzle (short index).
#define SWZ(r, c) ((((r) << 4) + ((c) ^ ((r) & 7))) << 3)
// 32-chunk variant (K=256 single-pass tiles).
__device__ inline int swz5(int r, int c) {
  return ((r << 5) + ((c & ~7) | ((c ^ r) & 7))) << 3;
}

// ---------------------------------------------------------------------------
// ws layout (bytes) — poison outside written regions is finite bf16, audited safe:
//   xmaj_bf  0        : 256x2048 bf16   rows>=210 poison (feeds discarded acc rows)
//   xmin_bf  1048576  : 256x2048 bf16
//   qs       2097152  : 256x1024 bf16   Qs (pre-scaled 1/32); rows>=210 poison
//   kwb      2621440  : 320x1024 bf16   0..209=K, 210..274=wk, 275..287=0, 288+ poison
//   vwt      3276800  : 1024x256 bf16   (V@Wo)^T [n][m]; cols>=210 poison (x zero A)
//   Abf      3801088  : 256x256  bf16   A padded, zeros outside 210x210
//   v        3932160  : 256x1024 bf16   V plain [m][k]; rows>=210 poison (clamped out)
//   Sp       4456448  : 224x320  f32    S'; cols>=288 / rows>=210 garbage (unread)
//   wqt      4743168  : 1024x2048 bf16  Wq^T
//   wkt      8937472  : 1024x2048 bf16  Wk^T
//   wvt      13131776 : 1024x2048 bf16  Wv^T
//   wot      17326080 : 1024x1024 bf16  Wo^T
// ---------------------------------------------------------------------------

// Prep: blocks [0,512) convert X_major/X_minor/wk to bf16 (+ zero kwb rows 275..287);
// blocks [512,2048) transpose+convert Wq/Wk/Wv (64x64 tiles); [2048,2304) Wo.
__global__ __launch_bounds__(256) void k_prep(const float* __restrict__ xmaj,
                                              const float* __restrict__ xmin,
                                              const float* __restrict__ wkin,
                                              const float* __restrict__ Wq,
                                              const float* __restrict__ Wk,
                                              const float* __restrict__ Wv,
                                              const float* __restrict__ Wo,
                                              short* __restrict__ xmaj_bf,
                                              short* __restrict__ xmin_bf,
                                              short* __restrict__ kwb,
                                              short* __restrict__ wqt,
                                              short* __restrict__ wkt,
                                              short* __restrict__ wvt,
                                              short* __restrict__ wot) {
  __shared__ short tile[64][72];  // stride 72 shorts: 16B-aligned rows
  int b = blockIdx.x, t = threadIdx.x;
  if (b < 512) {
    int idx = b * 256 + t;
    if (idx < 107520) {  // 210*2048/4
      float4 v = ((const float4*)xmaj)[idx];
      ((uint2*)xmaj_bf)[idx] = make_uint2(pack2(v.x, v.y), pack2(v.z, v.w));
      float4 u = ((const float4*)xmin)[idx];
      ((uint2*)xmin_bf)[idx] = make_uint2(pack2(u.x, u.y), pack2(u.z, u.w));
    }
    if (idx < 16640) {  // 65*1024/4
      float4 v = ((const float4*)wkin)[idx];
      ((uint2*)(kwb + 210 * 1024))[idx] = make_uint2(pack2(v.x, v.y), pack2(v.z, v.w));
    }
    if (idx < 1664) ((uint4*)(kwb + 275 * 1024))[idx] = make_uint4(0, 0, 0, 0);
    return;
  }
  const float* W;
  short* Wt;
  int kt, nt, dstK;
  if (b < 2048) {
    int wi = (b - 512) >> 9, tl = (b - 512) & 511;
    W = wi == 0 ? Wq : (wi == 1 ? Wk : Wv);
    Wt = wi == 0 ? wqt : (wi == 1 ? wkt : wvt);
    kt = tl >> 4; nt = tl & 15; dstK = 2048;
  } else {
    int tl = b - 2048;
    W = Wo; Wt = wot; kt = tl >> 4; nt = tl & 15; dstK = 1024;
  }
  int k0 = kt * 64, n0 = nt * 64;
  int kp = t >> 4, nl4 = (t & 15) * 4;
  for (int h = 0; h < 2; ++h) {
    int kpp = kp + h * 16;
    const float* g = W + (size_t)(k0 + 2 * kpp) * 1024 + n0 + nl4;
    float4 u = *(const float4*)g;
    float4 v = *(const float4*)(g + 1024);
    *(unsigned*)&tile[nl4 + 0][2 * kpp] = pack2(u.x, v.x);
    *(unsigned*)&tile[nl4 + 1][2 * kpp] = pack2(u.y, v.y);
    *(unsigned*)&tile[nl4 + 2][2 * kpp] = pack2(u.z, v.z);
    *(unsigned*)&tile[nl4 + 3][2 * kpp] = pack2(u.w, v.w);
  }
  __syncthreads();
  int nl = t >> 2, cq = t & 3;
  for (int h = 0; h < 2; ++h) {
    int c = cq + h * 4;
    *(uint4*)(Wt + (size_t)(n0 + nl) * dstK + k0 + c * 8) = *(const uint4*)&tile[nl][c * 8];
  }
}

// QKV: [Xmaj@Wq*scale | Xmin@Wk | Xmin@Wv], all-bf16 async staging, BK=128, 16 phases.
// 192 blocks, XCD swizzle. V now stored PLAIN [m][k] (feeds VW as A-operand).
__global__ __launch_bounds__(256, 1) void k_qkv(const short* __restrict__ xmaj,
                                                const short* __restrict__ xmin,
                                                const short* __restrict__ wqt,
                                                const short* __restrict__ wkt,
                                                const short* __restrict__ wvt,
                                                short* __restrict__ qs,
                                                short* __restrict__ kwb,
                                                short* __restrict__ v) {
  __shared__ short As[64 * 128];
  __shared__ short Bs[64 * 128];
  int b = blockIdx.x, t = threadIdx.x;
  int x = b & 7, s = b >> 3;
  int ntile = x * 6 + (s >> 2), mtile = s & 3;
  int nn0 = ntile * 64;
  int mat = nn0 >> 10, ncol0 = nn0 & 1023, m0 = mtile * 64;
  const short* A = (mat == 0) ? xmaj : xmin;
  const short* Bt = (mat == 0) ? wqt : (mat == 1 ? wkt : wvt);
  int lane = t & 63, w = t >> 6;
  int wm = w >> 1, wn = w & 1;
  int l15 = lane & 15, l4 = lane >> 4;
  f32x4 acc[2][2] = {};

  for (int k0 = 0; k0 < 2048; k0 += 128) {
    __syncthreads();
#pragma unroll
    for (int j = 0; j < 4; ++j) {
      int sj = t + j * 256;
      int r = sj >> 4, cg = (sj & 15) ^ (r & 7);
      async_cp16(A + (size_t)(m0 + r) * 2048 + k0 + cg * 8, &As[(w * 64 + j * 256) * 8]);
    }
#pragma unroll
    for (int j = 0; j < 4; ++j) {
      int sj = t + j * 256;
      int r = sj >> 4, cg = (sj & 15) ^ (r & 7);
      async_cp16(Bt + (size_t)(ncol0 + r) * 2048 + k0 + cg * 8, &Bs[(w * 64 + j * 256) * 8]);
    }
    __syncthreads();
#pragma unroll
    for (int kk = 0; kk < 4; ++kk) {
      int c = kk * 4 + l4;
      int ra0 = wm * 32 + l15, ra1 = ra0 + 16;
      int rb0 = wn * 32 + l15, rb1 = rb0 + 16;
      bf16x8 a0 = *(const bf16x8*)&As[SWZ(ra0, c)];
      bf16x8 a1 = *(const bf16x8*)&As[SWZ(ra1, c)];
      bf16x8 b0 = *(const bf16x8*)&Bs[SWZ(rb0, c)];
      bf16x8 b1 = *(const bf16x8*)&Bs[SWZ(rb1, c)];
      acc[0][0] = MFMA16(a0, b0, acc[0][0]);
      acc[0][1] = MFMA16(a0, b1, acc[0][1]);
      acc[1][0] = MFMA16(a1, b0, acc[1][0]);
      acc[1][1] = MFMA16(a1, b1, acc[1][1]);
    }
  }

  float scale = (mat == 0) ? 0.03125f : 1.0f;
  short* dst = (mat == 0) ? qs : (mat == 1 ? kwb : v);
#pragma unroll
  for (int mi = 0; mi < 2; ++mi)
#pragma unroll
    for (int ni = 0; ni < 2; ++ni) {
      int r0 = m0 + wm * 32 + mi * 16 + l4 * 4;
      int c = ncol0 + wn * 32 + ni * 16 + l15;
      for (int j = 0; j < 4; ++j) {
        int r = r0 + j;
        if (r < 210) dst[r * 1024 + c] = f2bf(acc[mi][ni][j] * scale);
      }
    }
}

// k_mid: one launch, two independent groups.
//  blocks 0..34:  S' = Qs @ [K;wk]^T -> Sp[224][320] fp32 (32x64 tiles, BK=128, dbuf)
//  blocks 35..98: VW^T = (V @ Wo)^T -> vwt[1024][256] bf16 (64x64 tiles, K=1024, dbuf,
//                 transpose epilogue via LDS). VW depends only on V — runs concurrent
//                 with S', hiding its wall time.
__global__ __launch_bounds__(256, 1) void k_mid(const short* __restrict__ qs,
                                                const short* __restrict__ kwb,
                                                const short* __restrict__ v,
                                                const short* __restrict__ wot,
                                                float* __restrict__ Sp,
                                                short* __restrict__ vwt) {
  __shared__ short As[2][64 * 128];
  __shared__ short Bs[2][64 * 128];
  int b = blockIdx.x, t = threadIdx.x;
  int lane = t & 63, w = t >> 6;
  int l15 = lane & 15, l4 = lane >> 4;

  if (b < 35) {  // ---- S' ----
    int n0 = (b % 5) * 64, m0 = (b / 5) * 32;
    f32x4 acc[2] = {};
    auto issue = [&](int p) {
      int k0 = p * 128, d = p & 1;
#pragma unroll
      for (int j = 0; j < 2; ++j) {
        int sj = t + j * 256;
        int r = sj >> 4, cg = (sj & 15) ^ (r & 7);
        async_cp16(qs + (size_t)(m0 + r) * 1024 + k0 + cg * 8, &As[d][(j * 256 + w * 64) * 8]);
      }
#pragma unroll
      for (int j = 0; j < 4; ++j) {
        int sj = t + j * 256;
        int r = sj >> 4, cg = (sj & 15) ^ (r & 7);
        async_cp16(kwb + (size_t)(n0 + r) * 1024 + k0 + cg * 8, &Bs[d][(j * 256 + w * 64) * 8]);
      }
    };
    issue(0);
#pragma unroll 1
    for (int p = 0; p < 8; ++p) {
      __syncthreads();
      if (p < 7) issue(p + 1);
      int d = p & 1;
#pragma unroll
      for (int kk = 0; kk < 4; ++kk) {
        int c = kk * 4 + l4;
        bf16x8 a0 = *(const bf16x8*)&As[d][SWZ(l15, c)];
        bf16x8 a1 = *(const bf16x8*)&As[d][SWZ(16 + l15, c)];
        bf16x8 bb = *(const bf16x8*)&Bs[d][SWZ(w * 16 + l15, c)];
        acc[0] = MFMA16(a0, bb, acc[0]);
        acc[1] = MFMA16(a1, bb, acc[1]);
      }
    }
#pragma unroll
    for (int mi = 0; mi < 2; ++mi) {
      int r0 = m0 + mi * 16 + l4 * 4;
      int col = n0 + w * 16 + l15;
      for (int j = 0; j < 4; ++j) Sp[(r0 + j) * 320 + col] = acc[mi][j];
    }
  } else {  // ---- VW^T ----
    int bb = b - 35;
    int n0 = (bb & 15) * 64, m0 = (bb >> 4) * 64;
    int wm = w >> 1, wn = w & 1;
    f32x4 acc[2][2] = {};
    auto issue = [&](int p) {
      int k0 = p * 128, d = p & 1;
#pragma unroll
      for (int j = 0; j < 4; ++j) {
        int sj = t + j * 256;
        int r = sj >> 4, cg = (sj & 15) ^ (r & 7);
        async_cp16(v + (size_t)(m0 + r) * 1024 + k0 + cg * 8, &As[d][(j * 256 + w * 64) * 8]);
        async_cp16(wot + (size_t)(n0 + r) * 1024 + k0 + cg * 8, &Bs[d][(j * 256 + w * 64) * 8]);
      }
    };
    issue(0);
#pragma unroll 1
    for (int p = 0; p < 8; ++p) {
      __syncthreads();
      if (p < 7) issue(p + 1);
      int d = p & 1;
#pragma unroll
      for (int kk = 0; kk < 4; ++kk) {
        int c = kk * 4 + l4;
        int ra0 = wm * 32 + l15, ra1 = ra0 + 16;
        int rb0 = wn * 32 + l15, rb1 = rb0 + 16;
        bf16x8 a0 = *(const bf16x8*)&As[d][SWZ(ra0, c)];
        bf16x8 a1 = *(const bf16x8*)&As[d][SWZ(ra1, c)];
        bf16x8 b0 = *(const bf16x8*)&Bs[d][SWZ(rb0, c)];
        bf16x8 b1 = *(const bf16x8*)&Bs[d][SWZ(rb1, c)];
        acc[0][0] = MFMA16(a0, b0, acc[0][0]);
        acc[0][1] = MFMA16(a0, b1, acc[0][1]);
        acc[1][0] = MFMA16(a1, b0, acc[1][0]);
        acc[1][1] = MFMA16(a1, b1, acc[1][1]);
      }
    }
    // transpose epilogue: acc [m][n] -> vwt[n][m], via LDS (stride 72), m-clamped
    __syncthreads();
    short* scr = &As[0][0];
#pragma unroll
    for (int mi = 0; mi < 2; ++mi)
#pragma unroll
      for (int ni = 0; ni < 2; ++ni) {
        int nl = wn * 32 + ni * 16 + l15;
        int ml0 = wm * 32 + mi * 16 + l4 * 4;
        for (int j = 0; j < 4; ++j) scr[nl * 72 + ml0 + j] = f2bf(acc[mi][ni][j]);
      }
    __syncthreads();
    for (int h = 0; h < 2; ++h) {
      int idx = t + h * 256;
      int nl = idx >> 3, c8 = idx & 7;
      int mg0 = m0 + c8 * 8;
      short* dstp = vwt + (size_t)(n0 + nl) * 256 + mg0;
      if (mg0 + 8 <= 210) {
        *(uint4*)dstp = *(const uint4*)&scr[nl * 72 + c8 * 8];
      } else {
        for (int e = 0; e < 8; ++e)
          if (mg0 + e < 210) dstp[e] = scr[nl * 72 + c8 * 8 + e];
      }
    }
  }
}

// softmax rows: logits[i][j] = Sp[i][j] + Sp[i][210+table[i][j]]; fp32 A to d_out,
// bf16 Abf (all 256x256 written: zeros outside 210x210).
__global__ __launch_bounds__(256) void k_softmax(const float* __restrict__ Sp,
                                                 const int* __restrict__ table,
                                                 short* __restrict__ Abf,
                                                 float* __restrict__ outA) {
  int i = blockIdx.x, t = threadIdx.x;
  if (i >= 210) {
    Abf[i * 256 + t] = 0;
    return;
  }
  __shared__ float srow[288];
  __shared__ float red[4];
  for (int j = t; j < 288; j += 256) srow[j] = Sp[i * 320 + j];
  __syncthreads();
  float logit = -1e30f;
  if (t < 210) {
    int tb = table[i * 210 + t];
    logit = srow[t] + srow[210 + tb];
  }
  float m = logit;
  for (int o = 32; o; o >>= 1) m = fmaxf(m, __shfl_xor(m, o));
  if ((t & 63) == 0) red[t >> 6] = m;
  __syncthreads();
  m = fmaxf(fmaxf(red[0], red[1]), fmaxf(red[2], red[3]));
  float e = (t < 210) ? __expf(logit - m) : 0.0f;
  float s = e;
  for (int o = 32; o; o >>= 1) s += __shfl_xor(s, o);
  __syncthreads();
  if ((t & 63) == 0) red[t >> 6] = s;
  __syncthreads();
  s = red[0] + red[1] + red[2] + red[3];
  float a = e / s;
  Abf[i * 256 + t] = (t < 210) ? f2bf(a) : (short)0;
  if (t < 210) outA[i * 210 + t] = a;
}

// Final: Y = Abf @ VW^T. 64x64 tiles, grid(16,4), single K=256 pass. fp32 out.
__global__ __launch_bounds__(256, 1) void k_fin(const short* __restrict__ Abf,
                                                const short* __restrict__ vwt,
                                                float* __restrict__ outY) {
  __shared__ short As[64 * 256];
  __shared__ short Bs[64 * 256];
  int n0 = blockIdx.x * 64, m0 = blockIdx.y * 64;
  int t = threadIdx.x, lane = t & 63, w = t >> 6;
  int wm = w >> 1, wn = w & 1;
  int l15 = lane & 15, l4 = lane >> 4;

#pragma unroll
  for (int j = 0; j < 8; ++j) {
    int sj = t + j * 256;
    int r = sj >> 5, c = sj & 31;
    int cg = (c & ~7) | ((c ^ r) & 7);
    async_cp16(Abf + (size_t)(m0 + r) * 256 + cg * 8, &As[(j * 256 + w * 64) * 8]);
    async_cp16(vwt + (size_t)(n0 + r) * 256 + cg * 8, &Bs[(j * 256 + w * 64) * 8]);
  }
  __syncthreads();

  f32x4 acc[2][2] = {};
#pragma unroll
  for (int kk = 0; kk < 8; ++kk) {
    int c = kk * 4 + l4;
    int ra0 = wm * 32 + l15, ra1 = ra0 + 16;
    int rb0 = wn * 32 + l15, rb1 = rb0 + 16;
    bf16x8 a0 = *(const bf16x8*)&As[swz5(ra0, c)];
    bf16x8 a1 = *(const bf16x8*)&As[swz5(ra1, c)];
    bf16x8 b0 = *(const bf16x8*)&Bs[swz5(rb0, c)];
    bf16x8 b1 = *(const bf16x8*)&Bs[swz5(rb1, c)];
    acc[0][0] = MFMA16(a0, b0, acc[0][0]);
    acc[0][1] = MFMA16(a0, b1, acc[0][1]);
    acc[1][0] = MFMA16(a1, b0, acc[1][0]);
    acc[1][1] = MFMA16(a1, b1, acc[1][1]);
  }
#pragma unroll
  for (int mi = 0; mi < 2; ++mi)
#pragma unroll
    for (int ni = 0; ni < 2; ++ni) {
      int r0 = m0 + wm * 32 + mi * 16 + l4 * 4;
      int c = n0 + wn * 32 + ni * 16 + l15;
      for (int j = 0; j < 4; ++j) {
        int r = r0 + j;
        if (r < 210) outY[r * 1024 + c] = acc[mi][ni][j];
      }
    }
}

extern "C" void kernel_launch(void* const* d_in, const int* in_sizes, int n_in,
                              void* d_out, int out_size, void* d_ws, size_t ws_size,
                              hipStream_t stream) {
  const float* Xmaj = (const float*)d_in[0];
  const float* Xmin = (const float*)d_in[1];
  const float* Wq = (const float*)d_in[2];
  const float* Wk = (const float*)d_in[3];
  const float* Wv = (const float*)d_in[4];
  const float* Wo = (const float*)d_in[5];
  const float* wk = (const float*)d_in[6];
  const int* table = (const int*)d_in[7];

  char* ws = (char*)d_ws;
  short* xmaj_bf = (short*)(ws + 0);
  short* xmin_bf = (short*)(ws + 1048576);
  short* qs = (short*)(ws + 2097152);
  short* kwb = (short*)(ws + 2621440);
  short* vwt = (short*)(ws + 3276800);
  short* Abf = (short*)(ws + 3801088);
  short* v = (short*)(ws + 3932160);
  float* Sp = (float*)(ws + 4456448);
  short* wqt = (short*)(ws + 4743168);
  short* wkt = (short*)(ws + 8937472);
  short* wvt = (short*)(ws + 13131776);
  short* wot = (short*)(ws + 17326080);

  float* outY = (float*)d_out;           // 210*1024 fp32
  float* outA = (float*)d_out + 215040;  // 210*210 fp32

  k_prep<<<2304, 256, 0, stream>>>(Xmaj, Xmin, wk, Wq, Wk, Wv, Wo,
                                   xmaj_bf, xmin_bf, kwb, wqt, wkt, wvt, wot);
  k_qkv<<<192, 256, 0, stream>>>(xmaj_bf, xmin_bf, wqt, wkt, wvt, qs, kwb, v);
  k_mid<<<99, 256, 0, stream>>>(qs, kwb, v, wot, Sp, vwt);
  k_softmax<<<256, 256, 0, stream>>>(Sp, table, Abf, outA);
  k_fin<<<dim3(16, 4), 256, 0, stream>>>(Abf, vwt, outY);
}